// Round 5
// baseline (277.820 us; speedup 1.0000x reference)
//
#include <hip/hip_runtime.h>
#include <hip/hip_bf16.h>

typedef unsigned short u16;
typedef float f32x4 __attribute__((ext_vector_type(4)));
typedef float f32x16 __attribute__((ext_vector_type(16)));
typedef __bf16 bf16x8 __attribute__((ext_vector_type(8)));
typedef u16 u16x4 __attribute__((ext_vector_type(4)));

#define NPIX 4096
#define CDIM 512
#define LOG2E 1.4426950408889634f

static __device__ __forceinline__ u16 f2bf(float f) {
  return __builtin_bit_cast(u16, (__bf16)f);
}
static __device__ __forceinline__ float bf2f(u16 u) {
  unsigned int v = ((unsigned int)u) << 16;
  return __builtin_bit_cast(float, v);
}
static __device__ __forceinline__ f32x16 zero16() {
  f32x16 z;
#pragma unroll
  for (int i = 0; i < 16; ++i) z[i] = 0.0f;
  return z;
}
static __device__ __forceinline__ f32x16 mfma16(bf16x8 a, bf16x8 b, f32x16 c) {
  return __builtin_amdgcn_mfma_f32_32x32x16_bf16(a, b, c, 0, 0, 0);
}

// ---------------------------------------------------------------------------
// Kernel 1: fused QKV projection (validated R1-R4, unchanged from R4).
// ---------------------------------------------------------------------------
__global__ __launch_bounds__(640, 3) void proj_kernel(
    const float* __restrict__ x,
    const float* __restrict__ Wq, const float* __restrict__ bq,
    const float* __restrict__ Wk, const float* __restrict__ bk,
    const float* __restrict__ Wv, const float* __restrict__ bv,
    u16* __restrict__ qh, u16* __restrict__ ql,
    u16* __restrict__ kh, u16* __restrict__ vv)
{
  const int b = blockIdx.y;
  const int nbase = blockIdx.x * 64;
  const int tid = threadIdx.x;
  const int w = tid >> 6;
  const int lane = tid & 63;
  const int lhi = lane >> 5, llo = lane & 31;

  __shared__ float xs[2048];  // [32 k][64 n] fp32, 8 KB

  const float* xb = x + (size_t)b * CDIM * NPIX + nbase;

  const float* wrow[2];
#pragma unroll
  for (int rb = 0; rb < 2; ++rb) {
    int row = 64 * w + 32 * rb + llo;
    wrow[rb] = (row < 64) ? (Wq + (size_t)row * CDIM)
             : (row < 128) ? (Wk + (size_t)(row - 64) * CDIM)
                           : (Wv + (size_t)(row - 128) * CDIM);
  }

  f32x16 acc[2][2];
  acc[0][0] = zero16(); acc[0][1] = zero16();
  acc[1][0] = zero16(); acc[1][1] = zero16();

  for (int ks2 = 0; ks2 < 16; ++ks2) {
    __syncthreads();
    if (tid < 512) {
      int r = tid >> 4, ci = (tid & 15) << 2;
      *(f32x4*)&xs[r * 64 + ci] =
          *(const f32x4*)&xb[(size_t)(ks2 * 32 + r) * NPIX + ci];
    }
    __syncthreads();

#pragma unroll
    for (int kk = 0; kk < 2; ++kk) {
      const int ksoff = ks2 * 32 + kk * 16;
      bf16x8 af[2];
#pragma unroll
      for (int rb = 0; rb < 2; ++rb) {
        const float* wp = wrow[rb] + ksoff + 8 * lhi;
        f32x4 w0 = *(const f32x4*)(wp);
        f32x4 w1 = *(const f32x4*)(wp + 4);
#pragma unroll
        for (int j = 0; j < 4; ++j) { af[rb][j] = (__bf16)w0[j]; af[rb][4 + j] = (__bf16)w1[j]; }
      }
      bf16x8 bfr[2];
#pragma unroll
      for (int cb = 0; cb < 2; ++cb) {
        int n = 32 * cb + llo;
#pragma unroll
        for (int j = 0; j < 8; ++j)
          bfr[cb][j] = (__bf16)xs[(kk * 16 + 8 * lhi + j) * 64 + n];
      }
#pragma unroll
      for (int rb = 0; rb < 2; ++rb)
#pragma unroll
        for (int cb = 0; cb < 2; ++cb)
          acc[rb][cb] = mfma16(af[rb], bfr[cb], acc[rb][cb]);
    }
  }

  // Epilogue: C/D layout col = lane&31 (n), row = (r&3)+8*(r>>2)+4*lhi.
#pragma unroll
  for (int rb = 0; rb < 2; ++rb) {
#pragma unroll
    for (int cb = 0; cb < 2; ++cb) {
      int n = nbase + 32 * cb + llo;
#pragma unroll
      for (int gq = 0; gq < 4; ++gq) {
        int dr0 = 8 * gq + 4 * lhi;
        float vals[4];
#pragma unroll
        for (int jj = 0; jj < 4; ++jj) {
          int Mrow = 64 * w + 32 * rb + dr0 + jj;
          float bias = (Mrow < 64) ? bq[Mrow] : (Mrow < 128) ? bk[Mrow - 64] : bv[Mrow - 128];
          vals[jj] = acc[rb][cb][4 * gq + jj] + bias;
        }
        if (w == 0) {  // q: hi/lo pair, pre-scaled by log2(e)
          u16x4 hi, lo;
#pragma unroll
          for (int jj = 0; jj < 4; ++jj) {
            float vq = vals[jj] * LOG2E;
            hi[jj] = f2bf(vq);
            lo[jj] = f2bf(vq - bf2f(hi[jj]));
          }
          int o = 32 * rb + dr0;
          size_t off = ((size_t)b * NPIX + n) * 64 + o;
          *(u16x4*)(qh + off) = hi;
          *(u16x4*)(ql + off) = lo;
        } else if (w == 1) {  // k: hi only
          u16x4 hi;
#pragma unroll
          for (int jj = 0; jj < 4; ++jj) hi[jj] = f2bf(vals[jj]);
          int o = 32 * rb + dr0;
          size_t off = ((size_t)b * NPIX + n) * 64 + o;
          *(u16x4*)(kh + off) = hi;
        } else {
#pragma unroll
          for (int jj = 0; jj < 4; ++jj) {
            int c = 64 * w - 128 + 32 * rb + dr0 + jj;
            vv[((size_t)b * CDIM + c) * NPIX + n] = f2bf(vals[jj]);
          }
        }
      }
    }
  }
}

// ---------------------------------------------------------------------------
// Kernel 2: single-pass attention, ILP-maximized for the measured 1-block/CU
// regime (R4: occupancy pinned at 8 waves/CU regardless of resources).
// Grid 256 = 64 qtiles x 4 batch (no S duplication). 8 waves; each wave owns
// a 64q x 64ch output (4 f32x16 accs) and computes a 32q x 64k S strip.
// 256-key tiles, 16 iters, 1 barrier/iter, 80 MFMA/iter/wave (16 S + 64 PV).
// K register-double-buffered one full tile ahead (A/B sets; ~5000cy cover).
// At 2 waves/SIMD the VGPR budget is 256: launch_bounds(512,1), demand ~200.
// P: 2 x [64][256] bf16 LDS buffers (64 KB) + aliased reductions.
// ---------------------------------------------------------------------------

#define LOADK(KF, T) do {                                                     \
  _Pragma("unroll") for (int j_ = 0; j_ < 2; ++j_) {                          \
    size_t koff_ = kbl[j_] + (size_t)(T) * (256 * 64);                        \
    _Pragma("unroll") for (int s_ = 0; s_ < 4; ++s_)                          \
      KF[j_][s_] = *(const bf16x8*)(kh + koff_ + 16 * s_);                    \
  }                                                                           \
} while (0)

#define S_PHASE(KF, BUFB) do {                                                \
  _Pragma("unroll") for (int j_ = 0; j_ < 2; ++j_) {                          \
    f32x16 sacc_ = zero16();                                                  \
    _Pragma("unroll") for (int s_ = 0; s_ < 4; ++s_)                          \
      sacc_ = mfma16(qfh[s_], KF[j_][s_], sacc_);                             \
    _Pragma("unroll") for (int s_ = 0; s_ < 4; ++s_)                          \
      sacc_ = mfma16(qfl[s_], KF[j_][s_], sacc_);                             \
    _Pragma("unroll") for (int r_ = 0; r_ < 16; ++r_) {                       \
      float p_ = __builtin_amdgcn_exp2f(sacc_[r_]);                           \
      u16 pb_ = f2bf(p_);                                                     \
      l_part[r_] += bf2f(pb_);                                                \
      int row_ = 32 * rb_s + (r_ & 3) + 8 * (r_ >> 2) + 4 * lhi;              \
      int byt_ = (row_ * 512 + (32 * (kb0 + j_) + llo) * 2)                   \
                 ^ ((row_ & 15) << 4);                                        \
      *(u16*)((BUFB) + byt_) = pb_;                                           \
    }                                                                         \
  }                                                                           \
} while (0)

#define PV_PHASE(BUFB, T) do {                                                \
  _Pragma("unroll") for (int s_ = 0; s_ < 16; ++s_) {                         \
    int ko_ = (16 * s_ + 8 * lhi) * 2;                                        \
    int by0_ = (llo * 512 + ko_) ^ ((llo & 15) << 4);                         \
    int by1_ = ((32 + llo) * 512 + ko_) ^ ((llo & 15) << 4);                  \
    bf16x8 pa0_ = *(const bf16x8*)((BUFB) + by0_);                            \
    bf16x8 pa1_ = *(const bf16x8*)((BUFB) + by1_);                            \
    size_t vo_ = (size_t)(T) * 256 + 16 * s_;                                 \
    bf16x8 vf0_ = *(const bf16x8*)(vv + vb0 + vo_);                           \
    bf16x8 vf1_ = *(const bf16x8*)(vv + vb1 + vo_);                           \
    acc00 = mfma16(pa0_, vf0_, acc00);                                        \
    acc01 = mfma16(pa0_, vf1_, acc01);                                        \
    acc10 = mfma16(pa1_, vf0_, acc10);                                        \
    acc11 = mfma16(pa1_, vf1_, acc11);                                        \
  }                                                                           \
} while (0)

__global__ __launch_bounds__(512, 1) void attn_kernel(
    const u16* __restrict__ qh, const u16* __restrict__ ql,
    const u16* __restrict__ kh, const u16* __restrict__ vv,
    const float* __restrict__ x, const float* __restrict__ gamma,
    float* __restrict__ out)
{
  const int bid = blockIdx.x;
  const int sw = ((bid & 7) << 5) | (bid >> 3);  // bijective, 256 = 8*32
  const int batch = sw >> 6;
  const int qbase = (sw & 63) * 64;
  const int tid = threadIdx.x;
  const int w = tid >> 6;
  const int lane = tid & 63;
  const int lhi = lane >> 5, llo = lane & 31;
  const int rb_s = w & 1;        // S row half (2 quadrant-rows)
  const int kb0 = (w >> 1) * 2;  // first of this wave's two 32-key blocks (of 8)

  __shared__ alignas(16) char Psm[65536];  // 2 x [64 q][256 k] bf16, swizzled
  char* Pb0 = Psm;
  char* Pb1 = Psm + 32768;
  // Reductions alias buf0 (free after the last PV on buf0 + final barrier).
  float* lred = (float*)Psm;              // [64][4]
  float* rl_lds = (float*)(Psm + 1024);   // [64]

  bf16x8 qfh[4], qfl[4];
  {
    size_t qoff = ((size_t)batch * NPIX + qbase + 32 * rb_s + llo) * 64 + 8 * lhi;
#pragma unroll
    for (int s = 0; s < 4; ++s) {
      qfh[s] = *(const bf16x8*)(qh + qoff + 16 * s);
      qfl[s] = *(const bf16x8*)(ql + qoff + 16 * s);
    }
  }

  size_t kbl[2];
#pragma unroll
  for (int j = 0; j < 2; ++j)
    kbl[j] = ((size_t)batch * NPIX + 32 * (kb0 + j) + llo) * 64 + 8 * lhi;

  const size_t vb0 = ((size_t)batch * CDIM + 64 * w + llo) * NPIX + 8 * lhi;
  const size_t vb1 = vb0 + (size_t)32 * NPIX;

  f32x16 acc00 = zero16(), acc01 = zero16(), acc10 = zero16(), acc11 = zero16();
  float l_part[16];
#pragma unroll
  for (int r = 0; r < 16; ++r) l_part[r] = 0.0f;

  bf16x8 kfA[2][4], kfB[2][4];

  // Prologue: K(0)->A, K(1)->B in flight, S(0)->buf0.
  LOADK(kfA, 0);
  LOADK(kfB, 1);
  S_PHASE(kfA, Pb0);
  __syncthreads();

  // Main loop covers t = 1..14 (7 pairs). Odd t uses B, even t uses A.
  for (int tt = 0; tt < 7; ++tt) {
    const int t0 = 2 * tt + 1;  // odd
    LOADK(kfA, t0 + 1);         // K(t0+1) -> A (consumed next sub-iter)
    PV_PHASE(Pb0, t0 - 1);
    S_PHASE(kfB, Pb1);          // S(t0) with K(t0) from B
    __syncthreads();
    const int t1 = t0 + 1;      // even
    LOADK(kfB, t1 + 1);         // K(t1+1) -> B (t1+1 <= 15)
    PV_PHASE(Pb1, t1 - 1);
    S_PHASE(kfA, Pb0);          // S(t1) with K(t1) from A
    __syncthreads();
  }
  // t = 15 (odd, uses B loaded at t1=14):
  PV_PHASE(Pb0, 14);
  S_PHASE(kfB, Pb1);
  __syncthreads();
  PV_PHASE(Pb1, 15);

  // Denominator: reduce l_part over the 32 key-lanes, merge the 4 wave-pairs
  // (same rb_s) in LDS (aliased onto buf0 - last read by PV(14), pre-barrier).
#pragma unroll
  for (int d = 1; d < 32; d <<= 1)
#pragma unroll
    for (int r = 0; r < 16; ++r) l_part[r] += __shfl_xor(l_part[r], d, 64);
  if (llo == 0) {
#pragma unroll
    for (int r = 0; r < 16; ++r) {
      int row = 32 * rb_s + (r & 3) + 8 * (r >> 2) + 4 * lhi;
      lred[row * 4 + (w >> 1)] = l_part[r];
    }
  }
  __syncthreads();
  if (tid < 64)
    rl_lds[tid] = 1.0f / (lred[tid * 4 + 0] + lred[tid * 4 + 1] +
                          lred[tid * 4 + 2] + lred[tid * 4 + 3]);
  __syncthreads();

  const float g = gamma[0];
#pragma unroll
  for (int ab = 0; ab < 2; ++ab) {
#pragma unroll
    for (int cb = 0; cb < 2; ++cb) {
      const f32x16& a = (ab == 0) ? (cb == 0 ? acc00 : acc01)
                                  : (cb == 0 ? acc10 : acc11);
      int c = 64 * w + 32 * cb + llo;
#pragma unroll
      for (int gq = 0; gq < 4; ++gq) {
        int qrow = 32 * ab + 8 * gq + 4 * lhi;
        size_t off = ((size_t)batch * CDIM + c) * NPIX + qbase + qrow;
        f32x4 xv = *(const f32x4*)(x + off);
        f32x4 rlv = *(const f32x4*)&rl_lds[qrow];
        f32x4 ov;
#pragma unroll
        for (int jj = 0; jj < 4; ++jj)
          ov[jj] = g * a[4 * gq + jj] * rlv[jj] + xv[jj];
        *(f32x4*)(out + off) = ov;
      }
    }
  }
}

extern "C" void kernel_launch(void* const* d_in, const int* in_sizes, int n_in,
                              void* d_out, int out_size, void* d_ws, size_t ws_size,
                              hipStream_t stream) {
  (void)in_sizes; (void)n_in; (void)out_size; (void)ws_size;
  const float* x     = (const float*)d_in[0];
  const float* Wq    = (const float*)d_in[1];
  const float* bq    = (const float*)d_in[2];
  const float* Wk    = (const float*)d_in[3];
  const float* bk    = (const float*)d_in[4];
  const float* Wv    = (const float*)d_in[5];
  const float* bv    = (const float*)d_in[6];
  const float* gamma = (const float*)d_in[7];
  float* out = (float*)d_out;

  // Workspace layout (bytes): qh 0..2M, ql 2..4M, kh 4..6M, v 6..22M.
  char* ws = (char*)d_ws;
  u16* qh = (u16*)(ws);
  u16* ql = (u16*)(ws + (2u << 20));
  u16* kh = (u16*)(ws + (4u << 20));
  u16* vv = (u16*)(ws + (6u << 20));

  proj_kernel<<<dim3(64, 4), 640, 0, stream>>>(x, Wq, bq, Wk, bk, Wv, bv,
                                               qh, ql, kh, vv);
  attn_kernel<<<256, 512, 0, stream>>>(qh, ql, kh, vv, x, gamma, out);
}

// Round 6
// 241.259 us; speedup vs baseline: 1.1515x; 1.1515x over previous
//
#include <hip/hip_runtime.h>
#include <hip/hip_bf16.h>

typedef unsigned short u16;
typedef float f32x4 __attribute__((ext_vector_type(4)));
typedef float f32x16 __attribute__((ext_vector_type(16)));
typedef __bf16 bf16x8 __attribute__((ext_vector_type(8)));
typedef u16 u16x4 __attribute__((ext_vector_type(4)));

#define NPIX 4096
#define CDIM 512
#define LOG2E 1.4426950408889634f

static __device__ __forceinline__ u16 f2bf(float f) {
  return __builtin_bit_cast(u16, (__bf16)f);
}
static __device__ __forceinline__ float bf2f(u16 u) {
  unsigned int v = ((unsigned int)u) << 16;
  return __builtin_bit_cast(float, v);
}
static __device__ __forceinline__ f32x16 zero16() {
  f32x16 z;
#pragma unroll
  for (int i = 0; i < 16; ++i) z[i] = 0.0f;
  return z;
}
static __device__ __forceinline__ f32x16 mfma16(bf16x8 a, bf16x8 b, f32x16 c) {
  return __builtin_amdgcn_mfma_f32_32x32x16_bf16(a, b, c, 0, 0, 0);
}

// ---------------------------------------------------------------------------
// Kernel 1: fused QKV projection (validated R1-R5, unchanged).
// ---------------------------------------------------------------------------
__global__ __launch_bounds__(640, 3) void proj_kernel(
    const float* __restrict__ x,
    const float* __restrict__ Wq, const float* __restrict__ bq,
    const float* __restrict__ Wk, const float* __restrict__ bk,
    const float* __restrict__ Wv, const float* __restrict__ bv,
    u16* __restrict__ qh, u16* __restrict__ ql,
    u16* __restrict__ kh, u16* __restrict__ vv)
{
  const int b = blockIdx.y;
  const int nbase = blockIdx.x * 64;
  const int tid = threadIdx.x;
  const int w = tid >> 6;
  const int lane = tid & 63;
  const int lhi = lane >> 5, llo = lane & 31;

  __shared__ float xs[2048];  // [32 k][64 n] fp32, 8 KB

  const float* xb = x + (size_t)b * CDIM * NPIX + nbase;

  const float* wrow[2];
#pragma unroll
  for (int rb = 0; rb < 2; ++rb) {
    int row = 64 * w + 32 * rb + llo;
    wrow[rb] = (row < 64) ? (Wq + (size_t)row * CDIM)
             : (row < 128) ? (Wk + (size_t)(row - 64) * CDIM)
                           : (Wv + (size_t)(row - 128) * CDIM);
  }

  f32x16 acc[2][2];
  acc[0][0] = zero16(); acc[0][1] = zero16();
  acc[1][0] = zero16(); acc[1][1] = zero16();

  for (int ks2 = 0; ks2 < 16; ++ks2) {
    __syncthreads();
    if (tid < 512) {
      int r = tid >> 4, ci = (tid & 15) << 2;
      *(f32x4*)&xs[r * 64 + ci] =
          *(const f32x4*)&xb[(size_t)(ks2 * 32 + r) * NPIX + ci];
    }
    __syncthreads();

#pragma unroll
    for (int kk = 0; kk < 2; ++kk) {
      const int ksoff = ks2 * 32 + kk * 16;
      bf16x8 af[2];
#pragma unroll
      for (int rb = 0; rb < 2; ++rb) {
        const float* wp = wrow[rb] + ksoff + 8 * lhi;
        f32x4 w0 = *(const f32x4*)(wp);
        f32x4 w1 = *(const f32x4*)(wp + 4);
#pragma unroll
        for (int j = 0; j < 4; ++j) { af[rb][j] = (__bf16)w0[j]; af[rb][4 + j] = (__bf16)w1[j]; }
      }
      bf16x8 bfr[2];
#pragma unroll
      for (int cb = 0; cb < 2; ++cb) {
        int n = 32 * cb + llo;
#pragma unroll
        for (int j = 0; j < 8; ++j)
          bfr[cb][j] = (__bf16)xs[(kk * 16 + 8 * lhi + j) * 64 + n];
      }
#pragma unroll
      for (int rb = 0; rb < 2; ++rb)
#pragma unroll
        for (int cb = 0; cb < 2; ++cb)
          acc[rb][cb] = mfma16(af[rb], bfr[cb], acc[rb][cb]);
    }
  }

  // Epilogue: C/D layout col = lane&31 (n), row = (r&3)+8*(r>>2)+4*lhi.
#pragma unroll
  for (int rb = 0; rb < 2; ++rb) {
#pragma unroll
    for (int cb = 0; cb < 2; ++cb) {
      int n = nbase + 32 * cb + llo;
#pragma unroll
      for (int gq = 0; gq < 4; ++gq) {
        int dr0 = 8 * gq + 4 * lhi;
        float vals[4];
#pragma unroll
        for (int jj = 0; jj < 4; ++jj) {
          int Mrow = 64 * w + 32 * rb + dr0 + jj;
          float bias = (Mrow < 64) ? bq[Mrow] : (Mrow < 128) ? bk[Mrow - 64] : bv[Mrow - 128];
          vals[jj] = acc[rb][cb][4 * gq + jj] + bias;
        }
        if (w == 0) {  // q: hi/lo pair, pre-scaled by log2(e)
          u16x4 hi, lo;
#pragma unroll
          for (int jj = 0; jj < 4; ++jj) {
            float vq = vals[jj] * LOG2E;
            hi[jj] = f2bf(vq);
            lo[jj] = f2bf(vq - bf2f(hi[jj]));
          }
          int o = 32 * rb + dr0;
          size_t off = ((size_t)b * NPIX + n) * 64 + o;
          *(u16x4*)(qh + off) = hi;
          *(u16x4*)(ql + off) = lo;
        } else if (w == 1) {  // k: hi only
          u16x4 hi;
#pragma unroll
          for (int jj = 0; jj < 4; ++jj) hi[jj] = f2bf(vals[jj]);
          int o = 32 * rb + dr0;
          size_t off = ((size_t)b * NPIX + n) * 64 + o;
          *(u16x4*)(kh + off) = hi;
        } else {
#pragma unroll
          for (int jj = 0; jj < 4; ++jj) {
            int c = 64 * w - 128 + 32 * rb + dr0 + jj;
            vv[((size_t)b * CDIM + c) * NPIX + n] = f2bf(vals[jj]);
          }
        }
      }
    }
  }
}

// ---------------------------------------------------------------------------
// Kernel 2: single-pass attention, ILP-maximized (R5 structure), register-fit.
// R5 post-mortem: allocator pinned VGPR=128 vs ~210 demand -> scratch spills
// (WRITE_SIZE 33->120 MB). Fixes: (1) single kf with issue-early (R4-proven;
// -32 VGPRs), (2) amdgpu_waves_per_eu(2) — min 2 waves/EU matches our 8-wave
// 1-block residency and raises the VGPR budget to >=256 for demand ~170.
// Grid 256 = 64 qtiles x 4 batch. 8 waves; each wave: 64q x 64ch output
// (4 f32x16 accs), 32q x 64k S strip. 256-key tiles, 16 iters, 1 barrier/iter,
// 80 MFMA/iter/wave (16 S + 64 PV).
// ---------------------------------------------------------------------------

#define LOADK(T) do {                                                         \
  _Pragma("unroll") for (int j_ = 0; j_ < 2; ++j_) {                          \
    size_t koff_ = kbl[j_] + (size_t)(T) * (256 * 64);                        \
    _Pragma("unroll") for (int s_ = 0; s_ < 4; ++s_)                          \
      kf[j_][s_] = *(const bf16x8*)(kh + koff_ + 16 * s_);                    \
  }                                                                           \
} while (0)

#define S_PHASE(BUFB) do {                                                    \
  _Pragma("unroll") for (int j_ = 0; j_ < 2; ++j_) {                          \
    f32x16 sacc_ = zero16();                                                  \
    _Pragma("unroll") for (int s_ = 0; s_ < 4; ++s_)                          \
      sacc_ = mfma16(qfh[s_], kf[j_][s_], sacc_);                             \
    _Pragma("unroll") for (int s_ = 0; s_ < 4; ++s_)                          \
      sacc_ = mfma16(qfl[s_], kf[j_][s_], sacc_);                             \
    _Pragma("unroll") for (int r_ = 0; r_ < 16; ++r_) {                       \
      float p_ = __builtin_amdgcn_exp2f(sacc_[r_]);                           \
      u16 pb_ = f2bf(p_);                                                     \
      l_part[r_] += bf2f(pb_);                                                \
      int row_ = 32 * rb_s + (r_ & 3) + 8 * (r_ >> 2) + 4 * lhi;              \
      int byt_ = (row_ * 512 + (32 * (kb0 + j_) + llo) * 2)                   \
                 ^ ((row_ & 15) << 4);                                        \
      *(u16*)((BUFB) + byt_) = pb_;                                           \
    }                                                                         \
  }                                                                           \
} while (0)

#define PV_PHASE(BUFB, T) do {                                                \
  _Pragma("unroll") for (int s_ = 0; s_ < 16; ++s_) {                         \
    int ko_ = (16 * s_ + 8 * lhi) * 2;                                        \
    int by0_ = (llo * 512 + ko_) ^ ((llo & 15) << 4);                         \
    int by1_ = ((32 + llo) * 512 + ko_) ^ ((llo & 15) << 4);                  \
    bf16x8 pa0_ = *(const bf16x8*)((BUFB) + by0_);                            \
    bf16x8 pa1_ = *(const bf16x8*)((BUFB) + by1_);                            \
    size_t vo_ = (size_t)(T) * 256 + 16 * s_;                                 \
    bf16x8 vf0_ = *(const bf16x8*)(vv + vb0 + vo_);                           \
    bf16x8 vf1_ = *(const bf16x8*)(vv + vb1 + vo_);                           \
    acc00 = mfma16(pa0_, vf0_, acc00);                                        \
    acc01 = mfma16(pa0_, vf1_, acc01);                                        \
    acc10 = mfma16(pa1_, vf0_, acc10);                                        \
    acc11 = mfma16(pa1_, vf1_, acc11);                                        \
  }                                                                           \
} while (0)

__global__ __launch_bounds__(512)
__attribute__((amdgpu_waves_per_eu(2)))
void attn_kernel(
    const u16* __restrict__ qh, const u16* __restrict__ ql,
    const u16* __restrict__ kh, const u16* __restrict__ vv,
    const float* __restrict__ x, const float* __restrict__ gamma,
    float* __restrict__ out)
{
  const int bid = blockIdx.x;
  const int sw = ((bid & 7) << 5) | (bid >> 3);  // bijective, 256 = 8*32
  const int batch = sw >> 6;
  const int qbase = (sw & 63) * 64;
  const int tid = threadIdx.x;
  const int w = tid >> 6;
  const int lane = tid & 63;
  const int lhi = lane >> 5, llo = lane & 31;
  const int rb_s = w & 1;        // S row half (2 quadrant-rows)
  const int kb0 = (w >> 1) * 2;  // first of this wave's two 32-key blocks (of 8)

  __shared__ alignas(16) char Psm[65536];  // 2 x [64 q][256 k] bf16, swizzled
  char* Pb0 = Psm;
  char* Pb1 = Psm + 32768;
  // Reductions alias buf0 (free after the last PV on buf0 + final barrier).
  float* lred = (float*)Psm;              // [64][4]
  float* rl_lds = (float*)(Psm + 1024);   // [64]

  bf16x8 qfh[4], qfl[4];
  {
    size_t qoff = ((size_t)batch * NPIX + qbase + 32 * rb_s + llo) * 64 + 8 * lhi;
#pragma unroll
    for (int s = 0; s < 4; ++s) {
      qfh[s] = *(const bf16x8*)(qh + qoff + 16 * s);
      qfl[s] = *(const bf16x8*)(ql + qoff + 16 * s);
    }
  }

  size_t kbl[2];
#pragma unroll
  for (int j = 0; j < 2; ++j)
    kbl[j] = ((size_t)batch * NPIX + 32 * (kb0 + j) + llo) * 64 + 8 * lhi;

  const size_t vb0 = ((size_t)batch * CDIM + 64 * w + llo) * NPIX + 8 * lhi;
  const size_t vb1 = vb0 + (size_t)32 * NPIX;

  f32x16 acc00 = zero16(), acc01 = zero16(), acc10 = zero16(), acc11 = zero16();
  float l_part[16];
#pragma unroll
  for (int r = 0; r < 16; ++r) l_part[r] = 0.0f;

  bf16x8 kf[2][4];  // single K fragment set, issue-early (R4-proven pattern)

  // Prologue: K(0) -> kf, S(0) -> buf0.
  LOADK(0);
  S_PHASE(Pb0);
  __syncthreads();

  // Main loop: t = 1..14. Odd t -> Pb1, even t -> Pb0. Within an iteration
  // LOADK(t) issues ~64 MFMAs before S_PHASE consumes kf (L2 latency hidden).
  for (int tt = 0; tt < 7; ++tt) {
    const int t0 = 2 * tt + 1;  // odd
    LOADK(t0);
    PV_PHASE(Pb0, t0 - 1);
    S_PHASE(Pb1);
    __syncthreads();
    const int t1 = t0 + 1;      // even
    LOADK(t1);
    PV_PHASE(Pb1, t1 - 1);
    S_PHASE(Pb0);
    __syncthreads();
  }
  // t = 15:
  LOADK(15);
  PV_PHASE(Pb0, 14);
  S_PHASE(Pb1);
  __syncthreads();
  PV_PHASE(Pb1, 15);

  // Denominator: reduce l_part over the 32 key-lanes, merge the 4 wave-pairs
  // (same rb_s) in LDS (aliased onto buf0 - last read by PV(14), pre-barrier).
#pragma unroll
  for (int d = 1; d < 32; d <<= 1)
#pragma unroll
    for (int r = 0; r < 16; ++r) l_part[r] += __shfl_xor(l_part[r], d, 64);
  if (llo == 0) {
#pragma unroll
    for (int r = 0; r < 16; ++r) {
      int row = 32 * rb_s + (r & 3) + 8 * (r >> 2) + 4 * lhi;
      lred[row * 4 + (w >> 1)] = l_part[r];
    }
  }
  __syncthreads();
  if (tid < 64)
    rl_lds[tid] = 1.0f / (lred[tid * 4 + 0] + lred[tid * 4 + 1] +
                          lred[tid * 4 + 2] + lred[tid * 4 + 3]);
  __syncthreads();

  const float g = gamma[0];
#pragma unroll
  for (int ab = 0; ab < 2; ++ab) {
#pragma unroll
    for (int cb = 0; cb < 2; ++cb) {
      const f32x16& a = (ab == 0) ? (cb == 0 ? acc00 : acc01)
                                  : (cb == 0 ? acc10 : acc11);
      int c = 64 * w + 32 * cb + llo;
#pragma unroll
      for (int gq = 0; gq < 4; ++gq) {
        int qrow = 32 * ab + 8 * gq + 4 * lhi;
        size_t off = ((size_t)batch * CDIM + c) * NPIX + qbase + qrow;
        f32x4 xv = *(const f32x4*)(x + off);
        f32x4 rlv = *(const f32x4*)&rl_lds[qrow];
        f32x4 ov;
#pragma unroll
        for (int jj = 0; jj < 4; ++jj)
          ov[jj] = g * a[4 * gq + jj] * rlv[jj] + xv[jj];
        *(f32x4*)(out + off) = ov;
      }
    }
  }
}

extern "C" void kernel_launch(void* const* d_in, const int* in_sizes, int n_in,
                              void* d_out, int out_size, void* d_ws, size_t ws_size,
                              hipStream_t stream) {
  (void)in_sizes; (void)n_in; (void)out_size; (void)ws_size;
  const float* x     = (const float*)d_in[0];
  const float* Wq    = (const float*)d_in[1];
  const float* bq    = (const float*)d_in[2];
  const float* Wk    = (const float*)d_in[3];
  const float* bk    = (const float*)d_in[4];
  const float* Wv    = (const float*)d_in[5];
  const float* bv    = (const float*)d_in[6];
  const float* gamma = (const float*)d_in[7];
  float* out = (float*)d_out;

  // Workspace layout (bytes): qh 0..2M, ql 2..4M, kh 4..6M, v 6..22M.
  char* ws = (char*)d_ws;
  u16* qh = (u16*)(ws);
  u16* ql = (u16*)(ws + (2u << 20));
  u16* kh = (u16*)(ws + (4u << 20));
  u16* vv = (u16*)(ws + (6u << 20));

  proj_kernel<<<dim3(64, 4), 640, 0, stream>>>(x, Wq, bq, Wk, bk, Wv, bv,
                                               qh, ql, kh, vv);
  attn_kernel<<<256, 512, 0, stream>>>(qh, ql, kh, vv, x, gamma, out);
}